// Round 13
// baseline (225.951 us; speedup 1.0000x reference)
//
#include <hip/hip_runtime.h>

typedef unsigned short u16;
typedef __bf16 bf16x8 __attribute__((ext_vector_type(8)));
typedef float   f32x4 __attribute__((ext_vector_type(4)));
typedef unsigned short u16x8 __attribute__((ext_vector_type(8)));

// ---------- helpers ----------
__device__ __forceinline__ u16 f2bf(float f) {
    unsigned int u = __builtin_bit_cast(unsigned int, f);
    u = u + 0x7FFFu + ((u >> 16) & 1u);   // round-to-nearest-even
    return (u16)(u >> 16);
}
__device__ __forceinline__ void gload16(const void* g, void* l) {
    __builtin_amdgcn_global_load_lds(
        (__attribute__((address_space(1))) void*)g,
        (__attribute__((address_space(3))) void*)l,
        16, 0, 0);
}

// ---------- kernel 1: fp32 -> bf16 cast (h) ----------
// Standalone (R7 lesson: merging with the VGPR-112 build branch dropped
// occupancy to 16% and cvt BW to 1.8 TB/s).
__global__ __launch_bounds__(256) void cvt_bf16(const float* __restrict__ x,
                                                u16* __restrict__ y) {
    int i = blockIdx.x * 256 + threadIdx.x;
    const f32x4* xp = (const f32x4*)x + (size_t)i * 2;
    f32x4 a = xp[0], b = xp[1];
    u16x8 o;
    o[0]=f2bf(a[0]); o[1]=f2bf(a[1]); o[2]=f2bf(a[2]); o[3]=f2bf(a[3]);
    o[4]=f2bf(b[0]); o[5]=f2bf(b[1]); o[6]=f2bf(b[2]); o[7]=f2bf(b[3]);
    ((u16x8*)y)[i] = o;
}

// ---------- small prep: WqT transpose | W2T build + ssq zero ----------
__global__ __launch_bounds__(256) void small_prep(
    const float* __restrict__ Wq, u16* __restrict__ WqT,
    const float* __restrict__ M0, const float* __restrict__ Wo,
    u16* __restrict__ W2T, float* __restrict__ ssq) {
    __shared__ __align__(16) char smem[16384];
    const int bid = blockIdx.x;
    const int tid = threadIdx.x;
    if (bid < 256) {
        u16 (*tile)[65] = (u16(*)[65])smem;
        const int c0 = (bid & 15) * 64;
        const int r0 = (bid >> 4) * 64;
        const int col = tid & 63;
        const int rb  = (tid >> 6) * 16;
        #pragma unroll
        for (int rr = 0; rr < 16; ++rr)
            tile[rb + rr][col] = f2bf(Wq[(size_t)(r0 + rb + rr) * 1024 + c0 + col]);
        __syncthreads();
        const int k = tid & 63;
        #pragma unroll
        for (int rr = 0; rr < 16; ++rr) {
            int n = c0 + rb + rr;
            WqT[(size_t)n * 1024 + r0 + k] = tile[k][rb + rr];
        }
    } else {
        const int local = bid - 256;             // 0..255
        const int jq = local & 3;
        const int hh = (local >> 2) & 15;
        const int bb = local >> 6;
        if (local < 128) ssq[local * 256 + tid] = 0.f;   // 128*256 = 32768
        const int j = jq * 256 + tid;
        float* m0s = (float*)smem;
        const float* m0p = M0 + ((size_t)bb * 16 + hh) * 4096;
        for (int i = tid; i < 4096; i += 256) m0s[i] = m0p[i];
        __syncthreads();
        float wo[64];
        #pragma unroll
        for (int e = 0; e < 64; ++e) wo[e] = Wo[(size_t)(hh * 64 + e) * 1024 + j];
        u16* outp = W2T + (size_t)bb * 1024 * 1024 + (size_t)j * 1024 + hh * 64;
        #pragma unroll 1
        for (int d = 0; d < 64; ++d) {
            float s = 0.f;
            #pragma unroll
            for (int e = 0; e < 64; ++e) s += m0s[d * 64 + e] * wo[e];
            outp[d] = f2bf(s);
        }
    }
}

// ---------- GEMM: C[M,N] = A[M,K] * Bt[N,K]^T, bf16 in, fp32 acc ----------
// R13: 128x128 tile, 256 threads (4 waves, 2Mx2N, 64x64/wave), 64 KiB LDS
// => TWO blocks co-resident per CU. Rationale: intra-block de-lockstep
// failed 3x (R5/R9 + vmcnt games) because all 8 waves shared one barrier
// domain; two independent blocks per CU overlap MFMA and LDS pipes
// naturally (m114: cross-domain waves co-schedule at ~max, not sum).
// Everything else is the R8-verified machinery, dimensionally halved:
// same st-swizzle (128B LDS rows, verbatim), same 8-phase order, same
// per-wave staging counts (2 gload16/half-tile) => vmcnt ledger identical
// (VMC4 @P4/P8; prologue VMC4). LGKM pre-barrier wait 8->4 (phases now
// issue 8 ds_reads, not 12). No job-chaining (grid 2048, sibling block +
// HW refill hide fills). Epilogue restores the R1-R7 vmcnt(0) drain:
// with >1 block-round per CU, a retiring block's in-flight wrap-stage
// gload_lds must not land in a successor block's LDS allocation.
template <int ACC_SSQ, int HAS_SCALE, typename CT>
__global__ __launch_bounds__(256, 2) void gemm128(const u16* __restrict__ A,
                                                  const u16* __restrict__ Bt,
                                                  CT* __restrict__ C,
                                                  float* __restrict__ ssq,
                                                  int N, int K,
                                                  int bt_batch_stride, int rpb_log2) {
    __shared__ __align__(16) u16 lds[32768];   // 65536 B: A 32KB + B 32KB (dbuf)
    const int tid  = threadIdx.x;
    const int lane = tid & 63;
    const int w    = tid >> 6;       // 0..3
    const int wm   = w >> 1;         // 0..1
    const int wn   = w & 1;          // 0..1

    char* const ldsb = (char*)lds;
    const int l3   = lane >> 3;
    const int co   = ((lane & 7) ^ l3) * 8;
    const int wdst = w * 2048;       // wave's 2KB share of an 8KB half-tile
    const int rm   = lane & 15;
    const int kq   = (lane >> 4) * 16;
    const int swzr = (rm & 7) << 4;
    const int cn   = lane & 15;
    const int rq   = (lane >> 4) * 4;

    // XCD swizzle: 2048 blocks = 256 mt x 8 nt; xcd owns 32 consecutive mt;
    // within an xcd, nt varies fastest -> 8 consecutive blocks share an
    // A-panel (L2-resident reuse).
    const int id  = blockIdx.x;
    const int xcd = id & 7;
    const int loc = id >> 3;                 // 0..255
    const int mt  = xcd * 32 + (loc >> 3);   // 0..255
    const int nt  = loc & 7;                 // 0..7
    const int m0  = mt * 128;
    const int n0  = nt * 128;
    const u16* Btb = Bt + (size_t)(m0 >> rpb_log2) * (size_t)bt_batch_stride;

    const u16* gA = A   + (size_t)(m0 + w * 16 + l3) * K + co;
    const u16* gB = Btb + (size_t)(n0 + w * 16 + l3) * K + co;

    // ---- staging (gload_lds; per-lane global src carries inverse swizzle) ----
    // half-tile = 64 rows x 64 cols bf16 = 8 KB; wave stages rows w*16+l3, +8.
    auto stA_ = [&](int buf, int h, int kt) {
        const u16* s = gA + (size_t)(h * 64) * K + kt * 64;
        char* d = ldsb + (buf * 2 + h) * 8192 + wdst;
        gload16(s, d);
        gload16(s + (size_t)8 * K, d + 1024);
    };
    auto stB_ = [&](int buf, int h, int kt) {
        const u16* s = gB + (size_t)(h * 64) * K + kt * 64;
        char* d = ldsb + 32768 + (buf * 2 + h) * 8192 + wdst;
        gload16(s, d);
        gload16(s + (size_t)8 * K, d + 1024);
    };

    // ---- fragment reads (swizzled ds_read_b128; 128-B rows, R8 swizzle) ----
    auto ldA = [&](int buf, int qm, int m, int ks) -> bf16x8 {
        const int row = qm * 32 + m * 16 + rm;          // within wm's 64-row half
        return *(const bf16x8*)(ldsb + (buf * 2 + wm) * 8192 + row * 128
                                + ((ks * 64 + kq) ^ swzr));
    };
    auto ldB = [&](int buf, int qn, int n, int ks) -> bf16x8 {
        const int row = qn * 32 + n * 16 + rm;          // within wn's 64-col half
        return *(const bf16x8*)(ldsb + 32768 + (buf * 2 + wn) * 8192
                                + row * 128 + ((ks * 64 + kq) ^ swzr));
    };

    f32x4 acc[4][4] = {};
    bf16x8 a[4];
    bf16x8 b[2][4];

#define LOADA(buf, qm)                                                         \
    { _Pragma("unroll") for (int m_ = 0; m_ < 2; ++m_) {                       \
        _Pragma("unroll") for (int k_ = 0; k_ < 2; ++k_)                       \
            a[m_ * 2 + k_] = ldA(buf, qm, m_, k_); } }
#define LOADB(buf, qn)                                                         \
    { _Pragma("unroll") for (int n_ = 0; n_ < 2; ++n_) {                       \
        _Pragma("unroll") for (int k_ = 0; k_ < 2; ++k_)                       \
            b[qn][n_ * 2 + k_] = ldB(buf, qn, n_, k_); } }
#define MFMAQ(qm, qn)                                                          \
    { __builtin_amdgcn_s_setprio(1);                                           \
      _Pragma("unroll") for (int m_ = 0; m_ < 2; ++m_) {                       \
        _Pragma("unroll") for (int n_ = 0; n_ < 2; ++n_) {                     \
          _Pragma("unroll") for (int k_ = 0; k_ < 2; ++k_)                     \
            acc[(qm) * 2 + m_][(qn) * 2 + n_] =                                \
                __builtin_amdgcn_mfma_f32_16x16x32_bf16(                       \
                    a[m_ * 2 + k_], b[qn][n_ * 2 + k_],                        \
                    acc[(qm) * 2 + m_][(qn) * 2 + n_], 0, 0, 0); } }           \
      __builtin_amdgcn_s_setprio(0); }
#define LGKM4 asm volatile("s_waitcnt lgkmcnt(4)" ::: "memory")
#define LGKM0 asm volatile("s_waitcnt lgkmcnt(0)" ::: "memory")
#define VMC4  asm volatile("s_waitcnt vmcnt(4)" ::: "memory")
#define BAR   __builtin_amdgcn_s_barrier()

    const int nkt = K >> 6;          // 16
    const int nit = nkt >> 1;        // 8

    // ---- prologue: tile0 (4 halves) + tile1 (B halves) ----
    stA_(0, 0, 0); stA_(0, 1, 0); stB_(0, 0, 0); stB_(0, 1, 0);
    stB_(1, 0, 1); stB_(1, 1, 1);
    VMC4;                            // tile0's 8 loads done; B(T1):4 in flight
    BAR;

    #pragma unroll 1
    for (int i = 0; i < nit; ++i) {
        const int T1 = 2 * i + 1;
        int T2 = 2 * i + 2; if (T2 >= nkt) T2 -= nkt;   // wrap: waste-stage
        int T3 = 2 * i + 3; if (T3 >= nkt) T3 -= nkt;

        // P1
        LOADA(0, 0); LOADB(0, 0);
        stA_(1, 0, T1);
        LGKM4; BAR; LGKM0;
        MFMAQ(0, 0); BAR;
        // P2
        LOADB(0, 1);
        stA_(1, 1, T1);
        BAR; LGKM0;
        MFMAQ(0, 1); BAR;
        // P3
        LOADA(0, 1);
        stB_(0, 0, T2);
        BAR; LGKM0;
        MFMAQ(1, 0); BAR;
        // P4  (drains A(T1):4; leaves B(T2):4 in flight)
        stB_(0, 1, T2);
        VMC4; BAR;
        MFMAQ(1, 1); BAR;
        // P5
        LOADA(1, 0); LOADB(1, 0);
        stA_(0, 0, T2);
        LGKM4; BAR; LGKM0;
        MFMAQ(0, 0); BAR;
        // P6
        LOADB(1, 1);
        stA_(0, 1, T2);
        BAR; LGKM0;
        MFMAQ(0, 1); BAR;
        // P7
        LOADA(1, 1);
        stB_(1, 0, T3);
        BAR; LGKM0;
        MFMAQ(1, 0); BAR;
        // P8  (drains A(T2):4; leaves B(T3):4)
        stB_(1, 1, T3);
        VMC4; BAR;
        MFMAQ(1, 1); BAR;
    }
#undef LOADA
#undef LOADB
#undef MFMAQ
#undef LGKM4
#undef LGKM0
#undef VMC4
#undef BAR

    // ---- epilogue: drain wrap-stages (REQUIRED: successor block reuses
    // this LDS allocation), then LDS-free stores ----
    asm volatile("s_waitcnt vmcnt(0)" ::: "memory");
    // C layout: col=lane&15, row=(lane>>4)*4+reg [m89]
    #pragma unroll
    for (int m = 0; m < 4; ++m) {
        const int rbase = wm * 64 + m * 16 + rq;
        #pragma unroll
        for (int r = 0; r < 4; ++r) {
            const int row = m0 + rbase + r;
            const size_t rowoff = (size_t)row * N;
            if constexpr (ACC_SSQ) {
                float s = 0.f;
                #pragma unroll
                for (int n = 0; n < 4; ++n) {
                    float x = acc[m][n][r];
                    s += x * x;
                    ((u16*)C)[rowoff + n0 + wn * 64 + n * 16 + cn] = f2bf(x);
                }
                s += __shfl_xor(s, 1);
                s += __shfl_xor(s, 2);
                s += __shfl_xor(s, 4);
                s += __shfl_xor(s, 8);
                if (cn == 0) atomicAdd(&ssq[row], s);   // 2 waves x 8 nt = 16/row
            } else {
                float sc = 1.0f;
                if constexpr (HAS_SCALE) {
                    float qv = ssq[row];                // L1/L2-hot
                    sc = 1.0f / fmaxf(sqrtf(qv), 1e-12f);
                }
                #pragma unroll
                for (int n = 0; n < 4; ++n)
                    C[rowoff + n0 + wn * 64 + n * 16 + cn] = acc[m][n][r] * sc;
            }
        }
    }
}

// ---------- launch ----------
// B=4, S=8192, HID=PROJ=1024, NH=16, HD=64; M = B*S = 32768
// hbf lives in d_out's first half (dead after gemm1 — gemm2 reads P from ws
// and overwrites all of d_out; stream-ordered, safe).
extern "C" void kernel_launch(void* const* d_in, const int* in_sizes, int n_in,
                              void* d_out, int out_size, void* d_ws, size_t ws_size,
                              hipStream_t stream) {
    const float* h  = (const float*)d_in[0];   // [4,8192,1024]
    const float* Wq = (const float*)d_in[1];   // [1024,1024]
    const float* Wo = (const float*)d_in[7];   // [1024,1024]
    const float* M0 = (const float*)d_in[8];   // [4,16,64,64]
    float* out = (float*)d_out;

    char* ws = (char*)d_ws;
    u16*   hbf  = (u16*)d_out;                 // 67,108,864 B (first half of out)
    u16*   P    = (u16*)(ws);                  // 67,108,864 B
    u16*   WqT  = (u16*)(ws + 67108864);       //  2,097,152 B
    u16*   W2T  = (u16*)(ws + 69206016);       //  8,388,608 B
    float* ssq  = (float*)(ws + 77594624);     //    131,072 B  (end: 77,725,696)

    const int N = 1024, K = 1024;

    cvt_bf16<<<16384, 256, 0, stream>>>(h, hbf);
    small_prep<<<512, 256, 0, stream>>>(Wq, WqT, M0, Wo, W2T, ssq);
    // P = h @ Wq (bf16, un-normalized) + per-row ssq via atomics
    gemm128<1, 0, u16><<<2048, 256, 0, stream>>>(
        hbf, WqT, P, ssq, N, K, 0, 0);
    // out = (1/max(sqrt(ssq),1e-12))[m] * (P @ W2T[batch]) ; batch = m >> 13
    gemm128<0, 1, float><<<2048, 256, 0, stream>>>(
        P, W2T, out, ssq, N, K, 1024 * 1024, 13);
}

// Round 14
// 198.382 us; speedup vs baseline: 1.1390x; 1.1390x over previous
//
#include <hip/hip_runtime.h>

typedef unsigned short u16;
typedef __bf16 bf16x8 __attribute__((ext_vector_type(8)));
typedef float   f32x4 __attribute__((ext_vector_type(4)));
typedef unsigned short u16x8 __attribute__((ext_vector_type(8)));

// ---------- helpers ----------
__device__ __forceinline__ u16 f2bf(float f) {
    unsigned int u = __builtin_bit_cast(unsigned int, f);
    u = u + 0x7FFFu + ((u >> 16) & 1u);   // round-to-nearest-even
    return (u16)(u >> 16);
}
__device__ __forceinline__ void gload16(const void* g, void* l) {
    __builtin_amdgcn_global_load_lds(
        (__attribute__((address_space(1))) void*)g,
        (__attribute__((address_space(3))) void*)l,
        16, 0, 0);
}

// ---------- kernel 1: fp32 -> bf16 cast (h) ----------
// Standalone (R7 lesson: merging with the VGPR-112 build branch dropped
// occupancy to 16% and cvt BW to 1.8 TB/s).
__global__ __launch_bounds__(256) void cvt_bf16(const float* __restrict__ x,
                                                u16* __restrict__ y) {
    int i = blockIdx.x * 256 + threadIdx.x;
    const f32x4* xp = (const f32x4*)x + (size_t)i * 2;
    f32x4 a = xp[0], b = xp[1];
    u16x8 o;
    o[0]=f2bf(a[0]); o[1]=f2bf(a[1]); o[2]=f2bf(a[2]); o[3]=f2bf(a[3]);
    o[4]=f2bf(b[0]); o[5]=f2bf(b[1]); o[6]=f2bf(b[2]); o[7]=f2bf(b[3]);
    ((u16x8*)y)[i] = o;
}

// ---------- small prep: WqT transpose | W2T build + ssq zero ----------
__global__ __launch_bounds__(256) void small_prep(
    const float* __restrict__ Wq, u16* __restrict__ WqT,
    const float* __restrict__ M0, const float* __restrict__ Wo,
    u16* __restrict__ W2T, float* __restrict__ ssq) {
    __shared__ __align__(16) char smem[16384];
    const int bid = blockIdx.x;
    const int tid = threadIdx.x;
    if (bid < 256) {
        u16 (*tile)[65] = (u16(*)[65])smem;
        const int c0 = (bid & 15) * 64;
        const int r0 = (bid >> 4) * 64;
        const int col = tid & 63;
        const int rb  = (tid >> 6) * 16;
        #pragma unroll
        for (int rr = 0; rr < 16; ++rr)
            tile[rb + rr][col] = f2bf(Wq[(size_t)(r0 + rb + rr) * 1024 + c0 + col]);
        __syncthreads();
        const int k = tid & 63;
        #pragma unroll
        for (int rr = 0; rr < 16; ++rr) {
            int n = c0 + rb + rr;
            WqT[(size_t)n * 1024 + r0 + k] = tile[k][rb + rr];
        }
    } else {
        const int local = bid - 256;             // 0..255
        const int jq = local & 3;
        const int hh = (local >> 2) & 15;
        const int bb = local >> 6;
        if (local < 128) ssq[local * 256 + tid] = 0.f;   // 128*256 = 32768
        const int j = jq * 256 + tid;
        float* m0s = (float*)smem;
        const float* m0p = M0 + ((size_t)bb * 16 + hh) * 4096;
        for (int i = tid; i < 4096; i += 256) m0s[i] = m0p[i];
        __syncthreads();
        float wo[64];
        #pragma unroll
        for (int e = 0; e < 64; ++e) wo[e] = Wo[(size_t)(hh * 64 + e) * 1024 + j];
        u16* outp = W2T + (size_t)bb * 1024 * 1024 + (size_t)j * 1024 + hh * 64;
        #pragma unroll 1
        for (int d = 0; d < 64; ++d) {
            float s = 0.f;
            #pragma unroll
            for (int e = 0; e < 64; ++e) s += m0s[d * 64 + e] * wo[e];
            outp[d] = f2bf(s);
        }
    }
}

// ---------- GEMM: C[M,N] = A[M,K] * Bt[N,K]^T, bf16 in, fp32 acc ----------
// R8-VERIFIED SESSION OPTIMUM (198.9-199.1 us total across two compiles;
// gemms ~79 us, MfmaUtil ~35%, bank conflicts 0).
// R1 8-phase loop (T2 swizzle, T3+T4 counted vmcnt, T5 setprio) + R8
// job-chaining: grid 256 (1 block/CU), each block runs tile b then b+256;
// the last K-iteration's wrap-stages prefetch job1's tile0 A+B and tile1 B:
//   peel-P4 vmcnt(4): drains A(buf1,15); leaves B_next(buf0) in flight
//   peel-P8 vmcnt(4): drains B_next(buf0)+A_next(buf0); leaves B_next(buf1)
// Epilogues are LDS-free (ssq via global atomics / scale via direct loads)
// => no syncthreads/vmcnt(0) between jobs; job0's epilogue stores overlap
// job1's P1-P3 and are drained harmlessly by job1's first counted vmcnt.
// [Final ledger — all measured neutral-or-worse vs this exact structure:
//  R2/R6 fp32-A staging (vmcnt queue pollution / bank conflicts),
//  R3 LDS-coalesced epilogue (+7us), R4 cross-GEMM fusion (+34us),
//  R5 epoch-shift (lockstep preserved), R9 anti-phasing (barrier-union),
//  R10/R11 direct-B (16x VMEM scatter), R13 128^2 dual-block (intensity).]
template <int ACC_SSQ, int HAS_SCALE, typename CT>
__global__ __launch_bounds__(512, 2) void gemm256(const u16* __restrict__ A,
                                                  const u16* __restrict__ Bt,
                                                  CT* __restrict__ C,
                                                  float* __restrict__ ssq,
                                                  int N, int K,
                                                  int bt_batch_stride, int rpb_log2) {
    __shared__ __align__(16) u16 lds[65536];   // 131072 B
    const int tid  = threadIdx.x;
    const int lane = tid & 63;
    const int w    = tid >> 6;       // 0..7
    const int wm   = w >> 2;         // 0..1
    const int wn   = w & 3;          // 0..3

    char* const ldsb = (char*)lds;
    const int l3   = lane >> 3;
    const int co   = ((lane & 7) ^ l3) * 8;
    const int wdst = w * 2048;
    const int rm   = lane & 15;
    const int kq   = (lane >> 4) * 16;
    const int swzr = (rm & 7) << 4;
    const int cn   = lane & 15;
    const int rq   = (lane >> 4) * 4;

    // XCD swizzle (512 logical tiles = 128 mt x 4 nt; id and id+256 share xcd)
    int m0, n0, m0n, n0n;
    const u16 *gA, *gB, *gAn, *gBn;
    auto setjob = [&](int idv, const u16*& pa, const u16*& pb, int& pm, int& pn) {
        const int xcd = idv & 7;
        const int loc = idv >> 3;
        const int mt  = xcd * 16 + (loc >> 2);
        const int nt  = loc & 3;
        pm = mt * 256;
        pn = nt * 256;
        const u16* btb = Bt + (size_t)(pm >> rpb_log2) * (size_t)bt_batch_stride;
        pa = A   + (size_t)(pm + w * 16 + l3) * K + co;
        pb = btb + (size_t)(pn + w * 16 + l3) * K + co;
    };
    setjob((int)blockIdx.x, gA, gB, m0, n0);

    // ---- staging (gload_lds; per-lane global src carries inverse swizzle) ----
    auto stA_ = [&](const u16* base, int buf, int h, int kt) {
        const u16* s = base + (size_t)(h * 128) * K + kt * 64;
        char* d = ldsb + (buf * 2 + h) * 16384 + wdst;
        gload16(s, d);
        gload16(s + (size_t)8 * K, d + 1024);
    };
    auto stB_ = [&](const u16* base, int buf, int h, int kt) {
        const u16* s = base + (size_t)(h * 128) * K + kt * 64;
        char* d = ldsb + 65536 + (buf * 2 + h) * 16384 + wdst;
        gload16(s, d);
        gload16(s + (size_t)8 * K, d + 1024);
    };

    // ---- fragment reads (swizzled ds_read_b128) ----
    auto ldA = [&](int buf, int qm, int m, int ks) -> bf16x8 {
        const int row = qm * 64 + m * 16 + rm;
        return *(const bf16x8*)(ldsb + (buf * 2 + wm) * 16384 + row * 128
                                + ((ks * 64 + kq) ^ swzr));
    };
    auto ldB = [&](int buf, int qn, int n, int ks) -> bf16x8 {
        const int row = (wn & 1) * 64 + qn * 32 + n * 16 + rm;
        return *(const bf16x8*)(ldsb + 65536 + (buf * 2 + (wn >> 1)) * 16384
                                + row * 128 + ((ks * 64 + kq) ^ swzr));
    };

    f32x4 acc[8][4] = {};
    bf16x8 a[8];
    bf16x8 b[2][4];

#define LOADA(buf, qm)                                                         \
    { _Pragma("unroll") for (int m_ = 0; m_ < 4; ++m_) {                       \
        _Pragma("unroll") for (int k_ = 0; k_ < 2; ++k_)                       \
            a[m_ * 2 + k_] = ldA(buf, qm, m_, k_); } }
#define LOADB(buf, qn)                                                         \
    { _Pragma("unroll") for (int n_ = 0; n_ < 2; ++n_) {                       \
        _Pragma("unroll") for (int k_ = 0; k_ < 2; ++k_)                       \
            b[qn][n_ * 2 + k_] = ldB(buf, qn, n_, k_); } }
#define MFMAQ(qm, qn)                                                          \
    { __builtin_amdgcn_s_setprio(1);                                           \
      _Pragma("unroll") for (int m_ = 0; m_ < 4; ++m_) {                       \
        _Pragma("unroll") for (int n_ = 0; n_ < 2; ++n_) {                     \
          _Pragma("unroll") for (int k_ = 0; k_ < 2; ++k_)                     \
            acc[(qm) * 4 + m_][(qn) * 2 + n_] =                                \
                __builtin_amdgcn_mfma_f32_16x16x32_bf16(                       \
                    a[m_ * 2 + k_], b[qn][n_ * 2 + k_],                        \
                    acc[(qm) * 4 + m_][(qn) * 2 + n_], 0, 0, 0); } }           \
      __builtin_amdgcn_s_setprio(0); }
#define LGKM8 asm volatile("s_waitcnt lgkmcnt(8)" ::: "memory")
#define LGKM0 asm volatile("s_waitcnt lgkmcnt(0)" ::: "memory")
#define VMC4  asm volatile("s_waitcnt vmcnt(4)" ::: "memory")
#define BAR   __builtin_amdgcn_s_barrier()

    // ---- prologue: tile0 (4 halves) + tile1 (B halves) of job0 ----
    stA_(gA, 0, 0, 0); stA_(gA, 0, 1, 0); stB_(gB, 0, 0, 0); stB_(gB, 0, 1, 0);
    stB_(gB, 1, 0, 1); stB_(gB, 1, 1, 1);
    VMC4;
    BAR;

    #pragma unroll 1
    for (int j = 0; j < 2; ++j) {
        if (j == 0) setjob((int)blockIdx.x + 256, gAn, gBn, m0n, n0n);
        else { gAn = gA; gBn = gB; }

        // ---- 7 normal iterations ----
        #pragma unroll 1
        for (int i = 0; i < 7; ++i) {
            const int T1 = 2 * i + 1;
            const int T2 = 2 * i + 2;
            const int T3 = 2 * i + 3;
            // P1
            LOADA(0, 0); LOADB(0, 0);
            stA_(gA, 1, 0, T1);
            LGKM8; BAR; LGKM0;
            MFMAQ(0, 0); BAR;
            // P2
            LOADB(0, 1);
            stA_(gA, 1, 1, T1);
            BAR; LGKM0;
            MFMAQ(0, 1); BAR;
            // P3
            LOADA(0, 1);
            stB_(gB, 0, 0, T2);
            BAR; LGKM0;
            MFMAQ(1, 0); BAR;
            // P4
            stB_(gB, 0, 1, T2);
            VMC4; BAR;
            MFMAQ(1, 1); BAR;
            // P5
            LOADA(1, 0); LOADB(1, 0);
            stA_(gA, 0, 0, T2);
            LGKM8; BAR; LGKM0;
            MFMAQ(0, 0); BAR;
            // P6
            LOADB(1, 1);
            stA_(gA, 0, 1, T2);
            BAR; LGKM0;
            MFMAQ(0, 1); BAR;
            // P7
            LOADA(1, 1);
            stB_(gB, 1, 0, T3);
            BAR; LGKM0;
            MFMAQ(1, 0); BAR;
            // P8
            stB_(gB, 1, 1, T3);
            VMC4; BAR;
            MFMAQ(1, 1); BAR;
        }

        // ---- peeled last iteration: stages target NEXT job's tiles ----
        // P1
        LOADA(0, 0); LOADB(0, 0);
        stA_(gA, 1, 0, 15);
        LGKM8; BAR; LGKM0;
        MFMAQ(0, 0); BAR;
        // P2
        LOADB(0, 1);
        stA_(gA, 1, 1, 15);
        BAR; LGKM0;
        MFMAQ(0, 1); BAR;
        // P3
        LOADA(0, 1);
        stB_(gBn, 0, 0, 0);
        BAR; LGKM0;
        MFMAQ(1, 0); BAR;
        // P4  (drains A(buf1,15); leaves B_next(buf0) in flight)
        stB_(gBn, 0, 1, 0);
        VMC4; BAR;
        MFMAQ(1, 1); BAR;
        // P5
        LOADA(1, 0); LOADB(1, 0);
        stA_(gAn, 0, 0, 0);
        LGKM8; BAR; LGKM0;
        MFMAQ(0, 0); BAR;
        // P6
        LOADB(1, 1);
        stA_(gAn, 0, 1, 0);
        BAR; LGKM0;
        MFMAQ(0, 1); BAR;
        // P7
        LOADA(1, 1);
        stB_(gBn, 1, 0, 1);
        BAR; LGKM0;
        MFMAQ(1, 0); BAR;
        // P8  (drains B_next(buf0)+A_next(buf0); leaves B_next(buf1))
        stB_(gBn, 1, 1, 1);
        VMC4; BAR;
        MFMAQ(1, 1); BAR;

        // ---- LDS-free epilogue (no syncthreads, no vmcnt drain) ----
        // C layout: col=lane&15, row=(lane>>4)*4+reg [m89]
        #pragma unroll
        for (int m = 0; m < 8; ++m) {
            const int rbase = wm * 128 + m * 16 + rq;
            #pragma unroll
            for (int r = 0; r < 4; ++r) {
                const int row = m0 + rbase + r;
                const size_t rowoff = (size_t)row * N;
                if constexpr (ACC_SSQ) {
                    float s = 0.f;
                    #pragma unroll
                    for (int n = 0; n < 4; ++n) {
                        float x = acc[m][n][r];
                        s += x * x;
                        ((u16*)C)[rowoff + n0 + wn * 64 + n * 16 + cn] = f2bf(x);
                    }
                    s += __shfl_xor(s, 1);
                    s += __shfl_xor(s, 2);
                    s += __shfl_xor(s, 4);
                    s += __shfl_xor(s, 8);
                    if (cn == 0) atomicAdd(&ssq[row], s);   // 16 adds/row total
                } else {
                    float sc = 1.0f;
                    if constexpr (HAS_SCALE) {
                        float qv = ssq[row];                // L1/L2-hot (1KB/block)
                        sc = 1.0f / fmaxf(sqrtf(qv), 1e-12f);
                    }
                    #pragma unroll
                    for (int n = 0; n < 4; ++n)
                        C[rowoff + n0 + wn * 64 + n * 16 + cn] = acc[m][n][r] * sc;
                }
            }
        }

        // ---- advance to job1 ----
        if (j == 0) {
            gA = gAn; gB = gBn; m0 = m0n; n0 = n0n;
            #pragma unroll
            for (int mm = 0; mm < 8; ++mm)
                #pragma unroll
                for (int nn = 0; nn < 4; ++nn)
                    acc[mm][nn] = f32x4{0.f, 0.f, 0.f, 0.f};
        }
    }
#undef LOADA
#undef LOADB
#undef MFMAQ
#undef LGKM8
#undef LGKM0
#undef VMC4
#undef BAR
}

// ---------- launch ----------
// B=4, S=8192, HID=PROJ=1024, NH=16, HD=64; M = B*S = 32768
// hbf lives in d_out's first half (dead after gemm1; gemm2 overwrites all
// of d_out — stream-ordered, safe).
extern "C" void kernel_launch(void* const* d_in, const int* in_sizes, int n_in,
                              void* d_out, int out_size, void* d_ws, size_t ws_size,
                              hipStream_t stream) {
    const float* h  = (const float*)d_in[0];   // [4,8192,1024]
    const float* Wq = (const float*)d_in[1];   // [1024,1024]
    const float* Wo = (const float*)d_in[7];   // [1024,1024]
    const float* M0 = (const float*)d_in[8];   // [4,16,64,64]
    float* out = (float*)d_out;

    char* ws = (char*)d_ws;
    u16*   hbf  = (u16*)d_out;                 // 67,108,864 B (first half of out)
    u16*   P    = (u16*)(ws);                  // 67,108,864 B
    u16*   WqT  = (u16*)(ws + 67108864);       //  2,097,152 B
    u16*   W2T  = (u16*)(ws + 69206016);       //  8,388,608 B
    float* ssq  = (float*)(ws + 77594624);     //    131,072 B  (end: 77,725,696)

    const int N = 1024, K = 1024;

    cvt_bf16<<<16384, 256, 0, stream>>>(h, hbf);
    small_prep<<<512, 256, 0, stream>>>(Wq, WqT, M0, Wo, W2T, ssq);
    // P = h @ Wq (bf16, un-normalized) + per-row ssq via atomics
    gemm256<1, 0, u16><<<256, 512, 0, stream>>>(
        hbf, WqT, P, ssq, N, K, 0, 0);
    // out = (1/max(sqrt(ssq),1e-12))[m] * (P @ W2T[batch]) ; batch = m >> 13
    gemm256<0, 1, float><<<256, 512, 0, stream>>>(
        P, W2T, out, ssq, N, K, 1024 * 1024, 13);
}